// Round 16
// baseline (204.512 us; speedup 1.0000x reference)
//
#include <hip/hip_runtime.h>

#define SEQ 2048
#define DIN 2048
#define NH 16
#define NKVH 4
#define DH 128
#define NQ 2048   /* NH*DH */
// q pre-scale = (1/sqrt(128)) * log2(e)  -> exp2 gives exp(qk/sqrt(d))
#define QSCALE2 0.1275174684f

typedef unsigned short ushort_t;
typedef unsigned int uint_t;
typedef __attribute__((ext_vector_type(8))) __bf16 bf16x8;
typedef __attribute__((ext_vector_type(8))) unsigned short ushort8;
typedef __attribute__((ext_vector_type(4))) unsigned short ushort4_t;
typedef __attribute__((ext_vector_type(4))) float f32x4;
typedef __attribute__((ext_vector_type(16))) float f32x16;

#if __has_builtin(__builtin_amdgcn_exp2f)
#define EXP2(x) __builtin_amdgcn_exp2f(x)
#else
#define EXP2(x) exp2f(x)
#endif

__device__ __forceinline__ float b2f(ushort_t u){ return __uint_as_float(((unsigned int)u)<<16); }
__device__ __forceinline__ ushort_t f2b(float f){
  unsigned int u = __float_as_uint(f);
  u += 0x7fff + ((u>>16)&1);            // RNE
  return (ushort_t)(u>>16);
}
__device__ __forceinline__ f32x4 mfma16(bf16x8 a, bf16x8 b, f32x4 c){
  return __builtin_amdgcn_mfma_f32_16x16x32_bf16(a, b, c, 0, 0, 0);
}
__device__ __forceinline__ f32x16 mfma32(bf16x8 a, bf16x8 b, f32x16 c){
  return __builtin_amdgcn_mfma_f32_32x32x16_bf16(a, b, c, 0, 0, 0);
}
__device__ __forceinline__ void gload16(const void* g, void* l){
  __builtin_amdgcn_global_load_lds((__attribute__((address_space(1))) void*)(void*)g,
                                   (__attribute__((address_space(3))) void*)l, 16, 0, 0);
}
__device__ __forceinline__ f32x16 zero16(){
  f32x16 z = {0.f,0.f,0.f,0.f,0.f,0.f,0.f,0.f,0.f,0.f,0.f,0.f,0.f,0.f,0.f,0.f};
  return z;
}

// ---------------------------------------------------------------- prep: trig table + dtype detect (fused)
// tab[s*64+j] = (cos(s*theta_j), sin(s*theta_j)); block 0 also detects dtype.
__global__ __launch_bounds__(256)
void prep(const ushort_t* __restrict__ wq, int* __restrict__ flag,
          float2* __restrict__ tab){
  const int i = blockIdx.x*256 + threadIdx.x;       // 0..131071
  const int s = i >> 6, j = i & 63;
  const float inv = __expf((float)j * -0.1439115683f);   // 10000^(-j/64)
  const float ang = (float)s * inv;
  tab[i] = make_float2(cosf(ang), sinf(ang));
  if (blockIdx.x == 0){
    __shared__ int any_big;
    if (threadIdx.x==0) any_big = 0;
    __syncthreads();
    int big = 0;
    for (int k=threadIdx.x; k<4096; k+=256){
      float v = b2f(wq[k]);
      if (!(fabsf(v) < 1.0f)) big = 1;              // catches NaN/inf too
    }
    if (big) atomicOr(&any_big, 1);
    __syncthreads();
    if (threadIdx.x==0) flag[0] = any_big ? 0 : 1;  // 0 = fp32 inputs, 1 = bf16
  }
}

// ---------------------------------------------------------------- fused convert: all 5 inputs -> bf16
__global__ __launch_bounds__(256)
void cvt_all(const void* __restrict__ x, const void* __restrict__ wq,
             const void* __restrict__ wk, const void* __restrict__ wv,
             const void* __restrict__ wo,
             ushort_t* __restrict__ xb, ushort_t* __restrict__ wqb,
             ushort_t* __restrict__ wkb, ushort_t* __restrict__ wvb,
             ushort_t* __restrict__ wob, const int* __restrict__ flag){
  int b = blockIdx.x;
  const void* src; ushort_t* dst; int off;
  if      (b < 2048){ src=x;  dst=xb;  off=b; }
  else if (b < 4096){ src=wq; dst=wqb; off=b-2048; }
  else if (b < 4608){ src=wk; dst=wkb; off=b-4096; }
  else if (b < 5120){ src=wv; dst=wvb; off=b-4608; }
  else              { src=wo; dst=wob; off=b-5120; }
  const int i = (off*256 + threadIdx.x)*8;
  if (flag[0]){
    *(ushort8*)&dst[i] = *(const ushort8*)((const ushort_t*)src + i);
  } else {
    f32x4 a = *(const f32x4*)((const float*)src + i);
    f32x4 c = *(const f32x4*)((const float*)src + i + 4);
    ushort8 w;
    #pragma unroll
    for (int e=0;e<4;e++){ w[e]=f2b(a[e]); w[4+e]=f2b(c[e]); }
    *(ushort8*)&dst[i] = w;
  }
}

// ---------------------------------------------------------------- sum of 4 bf16 partials -> bf16
__global__ __launch_bounds__(256)
void sum4(const ushort_t* __restrict__ pb, ushort_t* __restrict__ ab){
  const size_t PS = (size_t)SEQ*NQ;
  const int i = (blockIdx.x*256 + threadIdx.x)*8;
  ushort8 a = *(const ushort8*)&pb[i];
  ushort8 b = *(const ushort8*)&pb[PS + i];
  ushort8 c = *(const ushort8*)&pb[2*PS + i];
  ushort8 d = *(const ushort8*)&pb[3*PS + i];
  ushort8 w;
  #pragma unroll
  for (int e=0;e<8;e++)
    w[e] = f2b((b2f(a[e]) + b2f(b[e])) + (b2f(c[e]) + b2f(d[e])));
  *(ushort8*)&ab[i] = w;
}

// ---------------------------------------------------------------- bf16 tile stage helpers (global_load_lds)
__device__ __forceinline__ void stage128x32(const ushort_t* src, int ld, char* ldsbase, int tid){
  #pragma unroll
  for (int p=0;p<2;p++){
    int lin = p*4096 + tid*16;
    int r = lin>>6, cb = lin&63;
    gload16(src + (size_t)r*ld + (cb>>1), ldsbase + p*4096 + ((tid>>6)<<10));
  }
}
__device__ __forceinline__ void stage64x32(const ushort_t* src, int ld, char* ldsbase, int tid){
  int lin = tid*16;
  int r = lin>>6, cb = lin&63;
  gload16(src + (size_t)r*ld + (cb>>1), ldsbase + ((tid>>6)<<10));
}

// ---------------------------------------------------------------- fused QKV GEMM + table-RoPE + V-transpose
// 64x128 tile = one head's 64 rows. ny<16: q (rope via table, scaled);
// 16-19: k (rope via table); 20-23: v (written transposed to vt).
__global__ __launch_bounds__(256, 3)
void gemm_qkv(const ushort_t* __restrict__ X, const ushort_t* __restrict__ Wq,
              const ushort_t* __restrict__ Wk, const ushort_t* __restrict__ Wv,
              ushort_t* __restrict__ qb, ushort_t* __restrict__ kb,
              ushort_t* __restrict__ vt, const float2* __restrict__ tab){
  __shared__ __attribute__((aligned(16))) ushort_t lds_a[2][64*32];
  __shared__ __attribute__((aligned(16))) ushort_t lds_b[2][128*32];
  __shared__ __attribute__((aligned(16))) ushort_t lds_e[64*136];   // rope exchange
  const int tid = threadIdx.x;
  const int wid = tid>>6, lane = tid&63;
  const int lhi = lane>>4, llo = lane&15;
  // XCD-chunked: XCD x owns 3 consecutive W panels (96 blocks each)
  const int flat = blockIdx.x;                          // 0..767
  const int wf = (flat & 7)*96 + (flat >> 3);
  const int mb = (wf & 31)*64;
  const int ny = wf >> 5;                               // 0..23
  const ushort_t* W = (ny < 16) ? (Wq + (size_t)ny*128*DIN)
                    : (ny < 20) ? (Wk + (size_t)(ny-16)*128*DIN)
                    : (Wv + (size_t)(ny-20)*128*DIN);
  const int wr = (wid>>1)*32, wc = (wid&1)*64;

  f32x4 acc[2][4];
  #pragma unroll
  for (int i=0;i<2;i++)
    #pragma unroll
    for (int j=0;j<4;j++) acc[i][j] = (f32x4){0.f,0.f,0.f,0.f};

  auto stage = [&](int b, int t){
    stage64x32 (X + (size_t)mb*DIN + t*32, DIN, (char*)lds_a[b], tid);
    stage128x32(W + t*32, DIN, (char*)lds_b[b], tid);
  };

  stage(0, 0);
  __syncthreads();
  int cur = 0;
  for (int t=0; t<64; ++t){
    if (t < 63) stage(cur^1, t+1);
    bf16x8 af[2], bfr[4];
    #pragma unroll
    for (int i=0;i<2;i++) af[i]  = *(const bf16x8*)&lds_a[cur][(wr+i*16+llo)*32 + lhi*8];
    #pragma unroll
    for (int j=0;j<4;j++) bfr[j] = *(const bf16x8*)&lds_b[cur][(wc+j*16+llo)*32 + lhi*8];
    __builtin_amdgcn_s_setprio(1);
    #pragma unroll
    for (int i=0;i<2;i++)
      #pragma unroll
      for (int j=0;j<4;j++)
        acc[i][j] = mfma16(af[i], bfr[j], acc[i][j]);
    __builtin_amdgcn_s_setprio(0);
    __syncthreads();
    cur ^= 1;
  }
  if (ny < 20){
    // ---- fused RoPE via precomputed table (GPT-NeoX pairing c, c^64) ----
    #pragma unroll
    for (int i=0;i<2;i++)
      #pragma unroll
      for (int j=0;j<4;j++)
        #pragma unroll
        for (int rr=0;rr<4;rr++){
          int sl = wr + i*16 + lhi*4 + rr;
          int c  = wc + j*16 + llo;
          lds_e[sl*136 + c] = f2b(acc[i][j][rr]);
        }
    __syncthreads();
    const float scale = (ny < 16) ? QSCALE2 : 1.0f;
    #pragma unroll
    for (int i=0;i<2;i++)
      #pragma unroll
      for (int j=0;j<4;j++)
        #pragma unroll
        for (int rr=0;rr<4;rr++){
          int sl = wr + i*16 + lhi*4 + rr;
          int c  = wc + j*16 + llo;
          int s  = mb + sl;
          float v1 = acc[i][j][rr];
          float v2 = b2f(lds_e[sl*136 + (c^64)]);
          float2 cs = tab[(s<<6) + (c & 63)];
          float outv = (c < 64) ? (v1*cs.x - v2*cs.y) : (v1*cs.x + v2*cs.y);
          ushort_t val = f2b(outv*scale);
          if (ny < 16) qb[(size_t)s*NQ + ny*128 + c] = val;
          else         kb[(size_t)(ny-16)*SEQ*DH + (size_t)s*DH + c] = val;
        }
  } else {
    // v: store transposed directly vt[kv][d][s], 8B (4 consecutive s) per store
    const size_t vbase = (size_t)(ny-20)*DH*SEQ;
    #pragma unroll
    for (int i=0;i<2;i++)
      #pragma unroll
      for (int j=0;j<4;j++){
        int d = wc + j*16 + llo;
        int s = mb + wr + i*16 + lhi*4;
        ushort4_t w;
        #pragma unroll
        for (int rr=0;rr<4;rr++) w[rr] = f2b(acc[i][j][rr]);
        *(ushort4_t*)&vt[vbase + (size_t)d*SEQ + s] = w;
      }
  }
}

// ---------------------------------------------------------------- output GEMM, A bf16 (128x64 tile, A L2-resident per XCD)
__global__ __launch_bounds__(256, 2)
void gemm_plain_b16(const ushort_t* __restrict__ A, const ushort_t* __restrict__ Wo,
                    void* __restrict__ out, const int* __restrict__ flag){
  __shared__ __attribute__((aligned(16))) ushort_t lds_a[2][128*32];
  __shared__ __attribute__((aligned(16))) ushort_t lds_b[2][64*32];
  const int isb = flag[0];
  const int tid = threadIdx.x;
  const int wid = tid>>6, lane = tid&63;
  const int lhi = lane>>4, llo = lane&15;
  // XCD x owns mb stripes {2x, 2x+1} (A 1MB L2-resident), nb streams
  const int flat = blockIdx.x;                          // 0..511
  const int xcd = flat & 7, slot = flat >> 3;           // slot 0..63
  const int mb = (xcd*2 + (slot>>5))*128;
  const int nb = (slot&31)*64;
  const int wr = (wid>>1)*64, wc = (wid&1)*32;

  f32x4 acc[4][2];
  #pragma unroll
  for (int i=0;i<4;i++)
    #pragma unroll
    for (int j=0;j<2;j++) acc[i][j] = (f32x4){0.f,0.f,0.f,0.f};

  auto stage = [&](int b, int t){
    stage128x32(A  + (size_t)mb*NQ + t*32, NQ, (char*)lds_a[b], tid);
    stage64x32 (Wo + (size_t)nb*NQ + t*32, NQ, (char*)lds_b[b], tid);
  };

  stage(0, 0);
  __syncthreads();
  int cur = 0;
  for (int t=0; t<64; ++t){
    if (t < 63) stage(cur^1, t+1);
    bf16x8 af[4], bfr[2];
    #pragma unroll
    for (int i=0;i<4;i++) af[i]  = *(const bf16x8*)&lds_a[cur][(wr+i*16+llo)*32 + lhi*8];
    #pragma unroll
    for (int j=0;j<2;j++) bfr[j] = *(const bf16x8*)&lds_b[cur][(wc+j*16+llo)*32 + lhi*8];
    __builtin_amdgcn_s_setprio(1);
    #pragma unroll
    for (int i=0;i<4;i++)
      #pragma unroll
      for (int j=0;j<2;j++)
        acc[i][j] = mfma16(af[i], bfr[j], acc[i][j]);
    __builtin_amdgcn_s_setprio(0);
    __syncthreads();
    cur ^= 1;
  }
  #pragma unroll
  for (int i=0;i<4;i++)
    #pragma unroll
    for (int j=0;j<2;j++)
      #pragma unroll
      for (int rr=0;rr<4;rr++){
        int s  = mb + wr + i*16 + lhi*4 + rr;
        int nl = nb + wc + j*16 + llo;
        float v = acc[i][j][rr];
        if (isb) ((ushort_t*)out)[(size_t)s*NQ + nl] = f2b(v);
        else     ((float*)out)[(size_t)s*NQ + nl] = v;
      }
}

// ---------------------------------------------------------------- output GEMM, A fp32 (atomic fallback path)
__global__ __launch_bounds__(256, 2)
void gemm_plain_f32(const float* __restrict__ A, const ushort_t* __restrict__ Wo,
                    void* __restrict__ out, const int* __restrict__ flag){
  __shared__ __attribute__((aligned(16))) ushort_t lds_a[2][128*32];
  __shared__ __attribute__((aligned(16))) ushort_t lds_b[2][128*32];
  const int isb = flag[0];
  const int tid = threadIdx.x;
  const int wid = tid>>6, lane = tid&63;
  const int lhi = lane>>4, llo = lane&15;
  const int mb = blockIdx.x*128;
  const int nb = blockIdx.y*128;
  const int wr = (wid>>1)*64, wc = (wid&1)*64;
  const int r = tid>>1, c0 = (tid&1)*16;
  const float* Ab = A + (size_t)(mb+r)*NQ + c0;

  f32x4 acc[4][4];
  #pragma unroll
  for (int i=0;i<4;i++)
    #pragma unroll
    for (int j=0;j<4;j++) acc[i][j] = (f32x4){0.f,0.f,0.f,0.f};

  f32x4 raf[4];
  auto ldA = [&](int t){
    raf[0] = *(const f32x4*)(Ab + t*32);
    raf[1] = *(const f32x4*)(Ab + t*32 + 4);
    raf[2] = *(const f32x4*)(Ab + t*32 + 8);
    raf[3] = *(const f32x4*)(Ab + t*32 + 12);
  };
  auto stA = [&](ushort_t* lds){
    ushort8 w0, w1;
    #pragma unroll
    for (int e=0;e<4;e++){ w0[e]=f2b(raf[0][e]); w0[4+e]=f2b(raf[1][e]);
                           w1[e]=f2b(raf[2][e]); w1[4+e]=f2b(raf[3][e]); }
    *(ushort8*)&lds[r*32+c0]   = w0;
    *(ushort8*)&lds[r*32+c0+8] = w1;
  };

  ldA(0);
  stage128x32(Wo + (size_t)nb*NQ, NQ, (char*)lds_b[0], tid);
  stA(lds_a[0]);
  __syncthreads();
  int cur = 0;
  for (int t=0; t<64; ++t){
    const bool more = (t < 63);
    if (more){
      ldA(t+1);
      stage128x32(Wo + (size_t)nb*NQ + (t+1)*32, NQ, (char*)lds_b[cur^1], tid);
    }
    bf16x8 af[4], bfr[4];
    #pragma unroll
    for (int i=0;i<4;i++) af[i]  = *(const bf16x8*)&lds_a[cur][(wr+i*16+llo)*32 + lhi*8];
    #pragma unroll
    for (int j=0;j<4;j++) bfr[j] = *(const bf16x8*)&lds_b[cur][(wc+j*16+llo)*32 + lhi*8];
    __builtin_amdgcn_s_setprio(1);
    #pragma unroll
    for (int i=0;i<4;i++)
      #pragma unroll
      for (int j=0;j<4;j++)
        acc[i][j] = mfma16(af[i], bfr[j], acc[i][j]);
    __builtin_amdgcn_s_setprio(0);
    if (more) stA(lds_a[cur^1]);
    __syncthreads();
    cur ^= 1;
  }
  #pragma unroll
  for (int i=0;i<4;i++)
    #pragma unroll
    for (int j=0;j<4;j++)
      #pragma unroll
      for (int rr=0;rr<4;rr++){
        int s  = mb + wr + i*16 + lhi*4 + rr;
        int nl = nb + wc + j*16 + llo;
        float v = acc[i][j][rr];
        if (isb) ((ushort_t*)out)[(size_t)s*NQ + nl] = f2b(v);
        else     ((float*)out)[(size_t)s*NQ + nl] = v;
      }
}

// ---------------------------------------------------------------- Attention v16 (R13 body + T5 setprio on MFMA clusters)
// 1024 blocks (t,h,kv), single-buffered K/V (33KB LDS), launch_bounds(256,2)
// (~100 VGPR, no spill; 4 blocks/CU co-resident). Single-chain QK, per-rr
// edge mask, exp2 softmax, XCD-kv chunking, coset-balanced t permutation.
__global__ __launch_bounds__(256, 2)
void attn_kernel(const ushort_t* __restrict__ qb, const ushort_t* __restrict__ kb,
                 const ushort_t* __restrict__ vt, float* __restrict__ abf,
                 ushort_t* __restrict__ pb, int use_pb){
  __shared__ __attribute__((aligned(16))) ushort_t lds_k[64*128];
  __shared__ __attribute__((aligned(16))) ushort_t lds_v[128*64];
  __shared__ float lsum[4][32];
  const int tid = threadIdx.x;
  const int wid = tid>>6, lane = tid&63;
  const int l31 = lane&31, hi = lane>>5;
  const int flat = (int)(blockIdx.x + 16*blockIdx.y + 256*blockIdx.z);  // 0..1023
  const int xcd = flat & 7, slot = flat >> 3;                           // slot 0..127
  const int kv = xcd >> 1;                                              // kv per XCD pair
  const int idx = slot*2 + (xcd & 1);                                   // 0..255
  const int g = idx >> 4, h = idx & 15;
  // coset-balanced heavy-first permutation: cosets {g,g+4,g+8,g+12} sum to 30
  const int t = (g<4) ? 15-g : (g<8) ? 4+g : (g<12) ? g-4 : 15-g;
  const ushort_t* kbase = kb + (size_t)kv*SEQ*DH;
  const ushort_t* vbase = vt + (size_t)kv*DH*SEQ;
  const int NKT = 2*t + 2;
  const int qrow0 = t*128 + wid*32;
  const int qg = qrow0 + l31;

  bf16x8 qf[8];
  {
    const ushort_t* qp = qb + (size_t)qg*NQ + h*DH + hi*8;
    #pragma unroll
    for (int ks=0;ks<8;ks++) qf[ks] = *(const bf16x8*)(qp + ks*16);
  }
  f32x16 oacc[4];
  #pragma unroll
  for (int d=0;d<4;d++) oacc[d] = zero16();
  float psum = 0.f;

  for (int kt=0; kt<NKT; ++kt){
    __syncthreads();                    // all waves done reading previous tile
    // stage K [64][128] (swz ^((r&15)<<4)) + V^T [128][64] (swz ^((r&7)<<4))
    #pragma unroll
    for (int pp=0;pp<4;pp++){
      int lin = pp*4096 + tid*16;
      int rk = lin>>8, cbk = lin&255;
      int sck = cbk ^ ((rk&15)<<4);
      gload16(kbase + (size_t)(kt*64 + rk)*DH + (sck>>1), (char*)lds_k + pp*4096 + (wid<<10));
      int rv = lin>>7, cbv = lin&127;
      int scv = cbv ^ ((rv&7)<<4);
      gload16(vbase + (size_t)rv*SEQ + kt*64 + (scv>>1), (char*)lds_v + pp*4096 + (wid<<10));
    }
    __syncthreads();                    // staged (vmcnt(0) drained by barrier)

    #pragma unroll
    for (int ss=0;ss<2;ss++){
      const int kvb = kt*64 + ss*32;
      if (kvb > qrow0 + 31) continue;   // fully masked for this wave
      f32x16 sacc = zero16();
      __builtin_amdgcn_s_setprio(1);    // T5: favor MFMA wave vs staging waves
      #pragma unroll
      for (int ks=0;ks<8;ks++){
        int row = ss*32 + l31;
        int boff = row*256 + ((ks*32 + hi*16) ^ ((row&15)<<4));
        bf16x8 kf = *(const bf16x8*)((const char*)lds_k + boff);
        sacc = mfma32(kf, qf[ks], sacc);
      }
      __builtin_amdgcn_s_setprio(0);
      const bool edge = (kvb + 31 > qrow0);
      #pragma unroll
      for (int rr=0; rr<16; rr++){
        float e = EXP2(sacc[rr]);       // exp(qk/sqrt(d)): log2e folded into q scale
        if (edge){
          int kvg = kvb + (rr&3) + 8*(rr>>2) + 4*hi;
          if (kvg > qg) e = 0.f;
        }
        sacc[rr] = e;
        psum += e;
      }
      #pragma unroll
      for (int pk=0; pk<2; pk++){
        uint_t P0, P1, P2, P3;
        asm("v_cvt_pk_bf16_f32 %0, %1, %2" : "=v"(P0) : "v"(sacc[8*pk+0]), "v"(sacc[8*pk+1]));
        asm("v_cvt_pk_bf16_f32 %0, %1, %2" : "=v"(P1) : "v"(sacc[8*pk+2]), "v"(sacc[8*pk+3]));
        asm("v_cvt_pk_bf16_f32 %0, %1, %2" : "=v"(P2) : "v"(sacc[8*pk+4]), "v"(sacc[8*pk+5]));
        asm("v_cvt_pk_bf16_f32 %0, %1, %2" : "=v"(P3) : "v"(sacc[8*pk+6]), "v"(sacc[8*pk+7]));
        asm("v_permlane32_swap_b32 %0, %1" : "+v"(P0), "+v"(P2));
        asm("v_permlane32_swap_b32 %0, %1" : "+v"(P1), "+v"(P3));
        uint4 fu; fu.x = P0; fu.y = P1; fu.z = P2; fu.w = P3;
        bf16x8 pf = *(bf16x8*)&fu;
        __builtin_amdgcn_s_setprio(1);  // T5: PV MFMA cluster
        #pragma unroll
        for (int d=0; d<4; d++){
          int rowv = d*32 + l31;
          int bv = rowv*128 + ((ss*64 + pk*32 + hi*16) ^ ((rowv&7)<<4));
          bf16x8 vf = *(const bf16x8*)((const char*)lds_v + bv);
          oacc[d] = mfma32(pf, vf, oacc[d]);
        }
        __builtin_amdgcn_s_setprio(0);
      }
    }
  } // kt

  // finalize: row sums, scale by 0.25/l, write partial (or atomic fallback)
  {
    float tot = psum + __shfl_xor(psum, 32);
    lsum[wid][l31] = tot;
    if (use_pb){
      ushort_t* pbk = pb + (size_t)kv*SEQ*NQ + (size_t)h*DH;
      #pragma unroll
      for (int rr=0; rr<16; rr++){
        int qr = (rr&3) + 8*(rr>>2) + 4*hi;
        float sc = 0.25f / lsum[wid][qr];
        #pragma unroll
        for (int d=0; d<4; d++)
          pbk[(size_t)(qrow0 + qr)*NQ + d*32 + l31] = f2b(oacc[d][rr]*sc);
      }
    } else {
      #pragma unroll
      for (int rr=0; rr<16; rr++){
        int qr = (rr&3) + 8*(rr>>2) + 4*hi;
        float sc = 0.25f / lsum[wid][qr];
        #pragma unroll
        for (int d=0; d<4; d++)
          atomicAdd(&abf[(size_t)(qrow0 + qr)*NQ + h*DH + d*32 + l31], oacc[d][rr]*sc);
      }
    }
  }
}

// ---------------------------------------------------------------- launch
extern "C" void kernel_launch(void* const* d_in, const int* in_sizes, int n_in,
                              void* d_out, int out_size, void* d_ws, size_t ws_size,
                              hipStream_t stream) {
  const void* x  = d_in[0];
  const void* wq = d_in[1];
  const void* wk = d_in[2];
  const void* wv = d_in[3];
  const void* wo = d_in[4];
  char* ws = (char*)d_ws;
  const bool big_ws = (ws_size >= ((size_t)55<<20));

  if (big_ws){
    // q 0-8 | k 8-10 | tab 10-11 | vt 12-14 | pb0..3 14-46 | wob 46-54 | flag @54
    // overlays: xb 14-22, wqb 22-30, wkb 30-32, wvb 32-34 (dead after gemm_qkv,
    // before attn writes pb). ab = qbuf (dead after attn).
    ushort_t* qbuf = (ushort_t*)(ws);
    ushort_t* kbuf = (ushort_t*)(ws + ((size_t)8<<20));
    float2*   tab  = (float2*)  (ws + ((size_t)10<<20));
    ushort_t* vtb  = (ushort_t*)(ws + ((size_t)12<<20));
    ushort_t* pbuf = (ushort_t*)(ws + ((size_t)14<<20));
    ushort_t* xb   = (ushort_t*)(ws + ((size_t)14<<20));
    ushort_t* wqb  = (ushort_t*)(ws + ((size_t)22<<20));
    ushort_t* wkb  = (ushort_t*)(ws + ((size_t)30<<20));
    ushort_t* wvb  = (ushort_t*)(ws + ((size_t)32<<20));
    ushort_t* wob  = (ushort_t*)(ws + ((size_t)46<<20));
    ushort_t* ab   = qbuf;
    int* flag      = (int*)(ws + ((size_t)54<<20));

    hipLaunchKernelGGL(prep, dim3(512), dim3(256), 0, stream, (const ushort_t*)wq, flag, tab);
    hipLaunchKernelGGL(cvt_all, dim3(7168), dim3(256), 0, stream, x, wq, wk, wv, wo,
                       xb, wqb, wkb, wvb, wob, flag);
    hipLaunchKernelGGL(gemm_qkv, dim3(768), dim3(256), 0, stream, xb, wqb, wkb, wvb,
                       qbuf, kbuf, vtb, tab);
    hipLaunchKernelGGL(attn_kernel, dim3(16,16,4), dim3(256), 0, stream, qbuf, kbuf, vtb,
                       (float*)nullptr, pbuf, 1);
    hipLaunchKernelGGL(sum4, dim3(2048), dim3(256), 0, stream, pbuf, ab);
    hipLaunchKernelGGL(gemm_plain_b16, dim3(512), dim3(256), 0, stream, ab, wob, d_out, flag);
  } else {
    // atomic fallback: q 0-8 | k 8-10 | tab 10-11 | vt 12-14 | abf 14-30 fp32 |
    // xb 14-22, wqb 22-30 (overlay, dead before memset) | wkb 30-32 | wvb 32-34 |
    // wob 34-42 | flag @42
    ushort_t* qbuf = (ushort_t*)(ws);
    ushort_t* kbuf = (ushort_t*)(ws + ((size_t)8<<20));
    float2*   tab  = (float2*)  (ws + ((size_t)10<<20));
    ushort_t* vtb  = (ushort_t*)(ws + ((size_t)12<<20));
    float*    abf  = (float*)(ws + ((size_t)14<<20));
    ushort_t* xb   = (ushort_t*)(ws + ((size_t)14<<20));
    ushort_t* wqb  = (ushort_t*)(ws + ((size_t)22<<20));
    ushort_t* wkb  = (ushort_t*)(ws + ((size_t)30<<20));
    ushort_t* wvb  = (ushort_t*)(ws + ((size_t)32<<20));
    ushort_t* wob  = (ushort_t*)(ws + ((size_t)34<<20));
    int* flag      = (int*)(ws + ((size_t)42<<20));

    hipLaunchKernelGGL(prep, dim3(512), dim3(256), 0, stream, (const ushort_t*)wq, flag, tab);
    hipLaunchKernelGGL(cvt_all, dim3(7168), dim3(256), 0, stream, x, wq, wk, wv, wo,
                       xb, wqb, wkb, wvb, wob, flag);
    hipLaunchKernelGGL(gemm_qkv, dim3(768), dim3(256), 0, stream, xb, wqb, wkb, wvb,
                       qbuf, kbuf, vtb, tab);
    hipMemsetAsync(abf, 0, (size_t)SEQ*NQ*sizeof(float), stream);
    hipLaunchKernelGGL(attn_kernel, dim3(16,16,4), dim3(256), 0, stream, qbuf, kbuf, vtb,
                       abf, (ushort_t*)nullptr, 0);
    hipLaunchKernelGGL(gemm_plain_f32, dim3(16,16), dim3(256), 0, stream, abf, wob, d_out, flag);
  }
}

// Round 17
// 197.572 us; speedup vs baseline: 1.0351x; 1.0351x over previous
//
#include <hip/hip_runtime.h>

#define SEQ 2048
#define DIN 2048
#define NH 16
#define NKVH 4
#define DH 128
#define NQ 2048   /* NH*DH */
// q pre-scale = (1/sqrt(128)) * log2(e)  -> exp2 gives exp(qk/sqrt(d))
#define QSCALE2 0.1275174684f

typedef unsigned short ushort_t;
typedef unsigned int uint_t;
typedef __attribute__((ext_vector_type(8))) __bf16 bf16x8;
typedef __attribute__((ext_vector_type(8))) unsigned short ushort8;
typedef __attribute__((ext_vector_type(4))) unsigned short ushort4_t;
typedef __attribute__((ext_vector_type(4))) float f32x4;
typedef __attribute__((ext_vector_type(16))) float f32x16;

#if __has_builtin(__builtin_amdgcn_exp2f)
#define EXP2(x) __builtin_amdgcn_exp2f(x)
#else
#define EXP2(x) exp2f(x)
#endif

__device__ __forceinline__ float b2f(ushort_t u){ return __uint_as_float(((unsigned int)u)<<16); }
__device__ __forceinline__ ushort_t f2b(float f){
  unsigned int u = __float_as_uint(f);
  u += 0x7fff + ((u>>16)&1);            // RNE
  return (ushort_t)(u>>16);
}
__device__ __forceinline__ f32x4 mfma16(bf16x8 a, bf16x8 b, f32x4 c){
  return __builtin_amdgcn_mfma_f32_16x16x32_bf16(a, b, c, 0, 0, 0);
}
__device__ __forceinline__ f32x16 mfma32(bf16x8 a, bf16x8 b, f32x16 c){
  return __builtin_amdgcn_mfma_f32_32x32x16_bf16(a, b, c, 0, 0, 0);
}
__device__ __forceinline__ void gload16(const void* g, void* l){
  __builtin_amdgcn_global_load_lds((__attribute__((address_space(1))) void*)(void*)g,
                                   (__attribute__((address_space(3))) void*)l, 16, 0, 0);
}
__device__ __forceinline__ f32x16 zero16(){
  f32x16 z = {0.f,0.f,0.f,0.f,0.f,0.f,0.f,0.f,0.f,0.f,0.f,0.f,0.f,0.f,0.f,0.f};
  return z;
}

// ---------------------------------------------------------------- prep: trig table + dtype detect (fused)
// tab[s*64+j] = (cos(s*theta_j), sin(s*theta_j)); block 0 also detects dtype.
__global__ __launch_bounds__(256)
void prep(const ushort_t* __restrict__ wq, int* __restrict__ flag,
          float2* __restrict__ tab){
  const int i = blockIdx.x*256 + threadIdx.x;       // 0..131071
  const int s = i >> 6, j = i & 63;
  const float inv = __expf((float)j * -0.1439115683f);   // 10000^(-j/64)
  const float ang = (float)s * inv;
  tab[i] = make_float2(cosf(ang), sinf(ang));
  if (blockIdx.x == 0){
    __shared__ int any_big;
    if (threadIdx.x==0) any_big = 0;
    __syncthreads();
    int big = 0;
    for (int k=threadIdx.x; k<4096; k+=256){
      float v = b2f(wq[k]);
      if (!(fabsf(v) < 1.0f)) big = 1;              // catches NaN/inf too
    }
    if (big) atomicOr(&any_big, 1);
    __syncthreads();
    if (threadIdx.x==0) flag[0] = any_big ? 0 : 1;  // 0 = fp32 inputs, 1 = bf16
  }
}

// ---------------------------------------------------------------- fused convert: all 5 inputs -> bf16
__global__ __launch_bounds__(256)
void cvt_all(const void* __restrict__ x, const void* __restrict__ wq,
             const void* __restrict__ wk, const void* __restrict__ wv,
             const void* __restrict__ wo,
             ushort_t* __restrict__ xb, ushort_t* __restrict__ wqb,
             ushort_t* __restrict__ wkb, ushort_t* __restrict__ wvb,
             ushort_t* __restrict__ wob, const int* __restrict__ flag){
  int b = blockIdx.x;
  const void* src; ushort_t* dst; int off;
  if      (b < 2048){ src=x;  dst=xb;  off=b; }
  else if (b < 4096){ src=wq; dst=wqb; off=b-2048; }
  else if (b < 4608){ src=wk; dst=wkb; off=b-4096; }
  else if (b < 5120){ src=wv; dst=wvb; off=b-4608; }
  else              { src=wo; dst=wob; off=b-5120; }
  const int i = (off*256 + threadIdx.x)*8;
  if (flag[0]){
    *(ushort8*)&dst[i] = *(const ushort8*)((const ushort_t*)src + i);
  } else {
    f32x4 a = *(const f32x4*)((const float*)src + i);
    f32x4 c = *(const f32x4*)((const float*)src + i + 4);
    ushort8 w;
    #pragma unroll
    for (int e=0;e<4;e++){ w[e]=f2b(a[e]); w[4+e]=f2b(c[e]); }
    *(ushort8*)&dst[i] = w;
  }
}

// ---------------------------------------------------------------- sum of 4 bf16 partials -> bf16
__global__ __launch_bounds__(256)
void sum4(const ushort_t* __restrict__ pb, ushort_t* __restrict__ ab){
  const size_t PS = (size_t)SEQ*NQ;
  const int i = (blockIdx.x*256 + threadIdx.x)*8;
  ushort8 a = *(const ushort8*)&pb[i];
  ushort8 b = *(const ushort8*)&pb[PS + i];
  ushort8 c = *(const ushort8*)&pb[2*PS + i];
  ushort8 d = *(const ushort8*)&pb[3*PS + i];
  ushort8 w;
  #pragma unroll
  for (int e=0;e<8;e++)
    w[e] = f2b((b2f(a[e]) + b2f(b[e])) + (b2f(c[e]) + b2f(d[e])));
  *(ushort8*)&ab[i] = w;
}

// ---------------------------------------------------------------- bf16 tile stage helpers (global_load_lds)
__device__ __forceinline__ void stage128x32(const ushort_t* src, int ld, char* ldsbase, int tid){
  #pragma unroll
  for (int p=0;p<2;p++){
    int lin = p*4096 + tid*16;
    int r = lin>>6, cb = lin&63;
    gload16(src + (size_t)r*ld + (cb>>1), ldsbase + p*4096 + ((tid>>6)<<10));
  }
}
__device__ __forceinline__ void stage64x32(const ushort_t* src, int ld, char* ldsbase, int tid){
  int lin = tid*16;
  int r = lin>>6, cb = lin&63;
  gload16(src + (size_t)r*ld + (cb>>1), ldsbase + ((tid>>6)<<10));
}

// ---------------------------------------------------------------- fused QKV GEMM + table-RoPE + V-transpose
// 64x128 tile = one head's 64 rows. ny<16: q (rope via table, scaled);
// 16-19: k (rope via table); 20-23: v (written transposed to vt).
__global__ __launch_bounds__(256, 3)
void gemm_qkv(const ushort_t* __restrict__ X, const ushort_t* __restrict__ Wq,
              const ushort_t* __restrict__ Wk, const ushort_t* __restrict__ Wv,
              ushort_t* __restrict__ qb, ushort_t* __restrict__ kb,
              ushort_t* __restrict__ vt, const float2* __restrict__ tab){
  __shared__ __attribute__((aligned(16))) ushort_t lds_a[2][64*32];
  __shared__ __attribute__((aligned(16))) ushort_t lds_b[2][128*32];
  __shared__ __attribute__((aligned(16))) ushort_t lds_e[64*136];   // rope exchange
  const int tid = threadIdx.x;
  const int wid = tid>>6, lane = tid&63;
  const int lhi = lane>>4, llo = lane&15;
  // XCD-chunked: XCD x owns 3 consecutive W panels (96 blocks each)
  const int flat = blockIdx.x;                          // 0..767
  const int wf = (flat & 7)*96 + (flat >> 3);
  const int mb = (wf & 31)*64;
  const int ny = wf >> 5;                               // 0..23
  const ushort_t* W = (ny < 16) ? (Wq + (size_t)ny*128*DIN)
                    : (ny < 20) ? (Wk + (size_t)(ny-16)*128*DIN)
                    : (Wv + (size_t)(ny-20)*128*DIN);
  const int wr = (wid>>1)*32, wc = (wid&1)*64;

  f32x4 acc[2][4];
  #pragma unroll
  for (int i=0;i<2;i++)
    #pragma unroll
    for (int j=0;j<4;j++) acc[i][j] = (f32x4){0.f,0.f,0.f,0.f};

  auto stage = [&](int b, int t){
    stage64x32 (X + (size_t)mb*DIN + t*32, DIN, (char*)lds_a[b], tid);
    stage128x32(W + t*32, DIN, (char*)lds_b[b], tid);
  };

  stage(0, 0);
  __syncthreads();
  int cur = 0;
  for (int t=0; t<64; ++t){
    if (t < 63) stage(cur^1, t+1);
    bf16x8 af[2], bfr[4];
    #pragma unroll
    for (int i=0;i<2;i++) af[i]  = *(const bf16x8*)&lds_a[cur][(wr+i*16+llo)*32 + lhi*8];
    #pragma unroll
    for (int j=0;j<4;j++) bfr[j] = *(const bf16x8*)&lds_b[cur][(wc+j*16+llo)*32 + lhi*8];
    __builtin_amdgcn_s_setprio(1);
    #pragma unroll
    for (int i=0;i<2;i++)
      #pragma unroll
      for (int j=0;j<4;j++)
        acc[i][j] = mfma16(af[i], bfr[j], acc[i][j]);
    __builtin_amdgcn_s_setprio(0);
    __syncthreads();
    cur ^= 1;
  }
  if (ny < 20){
    // ---- fused RoPE via precomputed table (GPT-NeoX pairing c, c^64) ----
    #pragma unroll
    for (int i=0;i<2;i++)
      #pragma unroll
      for (int j=0;j<4;j++)
        #pragma unroll
        for (int rr=0;rr<4;rr++){
          int sl = wr + i*16 + lhi*4 + rr;
          int c  = wc + j*16 + llo;
          lds_e[sl*136 + c] = f2b(acc[i][j][rr]);
        }
    __syncthreads();
    const float scale = (ny < 16) ? QSCALE2 : 1.0f;
    #pragma unroll
    for (int i=0;i<2;i++)
      #pragma unroll
      for (int j=0;j<4;j++)
        #pragma unroll
        for (int rr=0;rr<4;rr++){
          int sl = wr + i*16 + lhi*4 + rr;
          int c  = wc + j*16 + llo;
          int s  = mb + sl;
          float v1 = acc[i][j][rr];
          float v2 = b2f(lds_e[sl*136 + (c^64)]);
          float2 cs = tab[(s<<6) + (c & 63)];
          float outv = (c < 64) ? (v1*cs.x - v2*cs.y) : (v1*cs.x + v2*cs.y);
          ushort_t val = f2b(outv*scale);
          if (ny < 16) qb[(size_t)s*NQ + ny*128 + c] = val;
          else         kb[(size_t)(ny-16)*SEQ*DH + (size_t)s*DH + c] = val;
        }
  } else {
    // v: store transposed directly vt[kv][d][s], 8B (4 consecutive s) per store
    const size_t vbase = (size_t)(ny-20)*DH*SEQ;
    #pragma unroll
    for (int i=0;i<2;i++)
      #pragma unroll
      for (int j=0;j<4;j++){
        int d = wc + j*16 + llo;
        int s = mb + wr + i*16 + lhi*4;
        ushort4_t w;
        #pragma unroll
        for (int rr=0;rr<4;rr++) w[rr] = f2b(acc[i][j][rr]);
        *(ushort4_t*)&vt[vbase + (size_t)d*SEQ + s] = w;
      }
  }
}

// ---------------------------------------------------------------- output GEMM, A bf16 (128x64 tile, A L2-resident per XCD)
__global__ __launch_bounds__(256, 2)
void gemm_plain_b16(const ushort_t* __restrict__ A, const ushort_t* __restrict__ Wo,
                    void* __restrict__ out, const int* __restrict__ flag){
  __shared__ __attribute__((aligned(16))) ushort_t lds_a[2][128*32];
  __shared__ __attribute__((aligned(16))) ushort_t lds_b[2][64*32];
  const int isb = flag[0];
  const int tid = threadIdx.x;
  const int wid = tid>>6, lane = tid&63;
  const int lhi = lane>>4, llo = lane&15;
  // XCD x owns mb stripes {2x, 2x+1} (A 1MB L2-resident), nb streams
  const int flat = blockIdx.x;                          // 0..511
  const int xcd = flat & 7, slot = flat >> 3;           // slot 0..63
  const int mb = (xcd*2 + (slot>>5))*128;
  const int nb = (slot&31)*64;
  const int wr = (wid>>1)*64, wc = (wid&1)*32;

  f32x4 acc[4][2];
  #pragma unroll
  for (int i=0;i<4;i++)
    #pragma unroll
    for (int j=0;j<2;j++) acc[i][j] = (f32x4){0.f,0.f,0.f,0.f};

  auto stage = [&](int b, int t){
    stage128x32(A  + (size_t)mb*NQ + t*32, NQ, (char*)lds_a[b], tid);
    stage64x32 (Wo + (size_t)nb*NQ + t*32, NQ, (char*)lds_b[b], tid);
  };

  stage(0, 0);
  __syncthreads();
  int cur = 0;
  for (int t=0; t<64; ++t){
    if (t < 63) stage(cur^1, t+1);
    bf16x8 af[4], bfr[2];
    #pragma unroll
    for (int i=0;i<4;i++) af[i]  = *(const bf16x8*)&lds_a[cur][(wr+i*16+llo)*32 + lhi*8];
    #pragma unroll
    for (int j=0;j<2;j++) bfr[j] = *(const bf16x8*)&lds_b[cur][(wc+j*16+llo)*32 + lhi*8];
    __builtin_amdgcn_s_setprio(1);
    #pragma unroll
    for (int i=0;i<4;i++)
      #pragma unroll
      for (int j=0;j<2;j++)
        acc[i][j] = mfma16(af[i], bfr[j], acc[i][j]);
    __builtin_amdgcn_s_setprio(0);
    __syncthreads();
    cur ^= 1;
  }
  #pragma unroll
  for (int i=0;i<4;i++)
    #pragma unroll
    for (int j=0;j<2;j++)
      #pragma unroll
      for (int rr=0;rr<4;rr++){
        int s  = mb + wr + i*16 + lhi*4 + rr;
        int nl = nb + wc + j*16 + llo;
        float v = acc[i][j][rr];
        if (isb) ((ushort_t*)out)[(size_t)s*NQ + nl] = f2b(v);
        else     ((float*)out)[(size_t)s*NQ + nl] = v;
      }
}

// ---------------------------------------------------------------- output GEMM, A fp32 (atomic fallback path)
__global__ __launch_bounds__(256, 2)
void gemm_plain_f32(const float* __restrict__ A, const ushort_t* __restrict__ Wo,
                    void* __restrict__ out, const int* __restrict__ flag){
  __shared__ __attribute__((aligned(16))) ushort_t lds_a[2][128*32];
  __shared__ __attribute__((aligned(16))) ushort_t lds_b[2][128*32];
  const int isb = flag[0];
  const int tid = threadIdx.x;
  const int wid = tid>>6, lane = tid&63;
  const int lhi = lane>>4, llo = lane&15;
  const int mb = blockIdx.x*128;
  const int nb = blockIdx.y*128;
  const int wr = (wid>>1)*64, wc = (wid&1)*64;
  const int r = tid>>1, c0 = (tid&1)*16;
  const float* Ab = A + (size_t)(mb+r)*NQ + c0;

  f32x4 acc[4][4];
  #pragma unroll
  for (int i=0;i<4;i++)
    #pragma unroll
    for (int j=0;j<4;j++) acc[i][j] = (f32x4){0.f,0.f,0.f,0.f};

  f32x4 raf[4];
  auto ldA = [&](int t){
    raf[0] = *(const f32x4*)(Ab + t*32);
    raf[1] = *(const f32x4*)(Ab + t*32 + 4);
    raf[2] = *(const f32x4*)(Ab + t*32 + 8);
    raf[3] = *(const f32x4*)(Ab + t*32 + 12);
  };
  auto stA = [&](ushort_t* lds){
    ushort8 w0, w1;
    #pragma unroll
    for (int e=0;e<4;e++){ w0[e]=f2b(raf[0][e]); w0[4+e]=f2b(raf[1][e]);
                           w1[e]=f2b(raf[2][e]); w1[4+e]=f2b(raf[3][e]); }
    *(ushort8*)&lds[r*32+c0]   = w0;
    *(ushort8*)&lds[r*32+c0+8] = w1;
  };

  ldA(0);
  stage128x32(Wo + (size_t)nb*NQ, NQ, (char*)lds_b[0], tid);
  stA(lds_a[0]);
  __syncthreads();
  int cur = 0;
  for (int t=0; t<64; ++t){
    const bool more = (t < 63);
    if (more){
      ldA(t+1);
      stage128x32(Wo + (size_t)nb*NQ + (t+1)*32, NQ, (char*)lds_b[cur^1], tid);
    }
    bf16x8 af[4], bfr[4];
    #pragma unroll
    for (int i=0;i<4;i++) af[i]  = *(const bf16x8*)&lds_a[cur][(wr+i*16+llo)*32 + lhi*8];
    #pragma unroll
    for (int j=0;j<4;j++) bfr[j] = *(const bf16x8*)&lds_b[cur][(wc+j*16+llo)*32 + lhi*8];
    __builtin_amdgcn_s_setprio(1);
    #pragma unroll
    for (int i=0;i<4;i++)
      #pragma unroll
      for (int j=0;j<4;j++)
        acc[i][j] = mfma16(af[i], bfr[j], acc[i][j]);
    __builtin_amdgcn_s_setprio(0);
    if (more) stA(lds_a[cur^1]);
    __syncthreads();
    cur ^= 1;
  }
  #pragma unroll
  for (int i=0;i<4;i++)
    #pragma unroll
    for (int j=0;j<4;j++)
      #pragma unroll
      for (int rr=0;rr<4;rr++){
        int s  = mb + wr + i*16 + lhi*4 + rr;
        int nl = nb + wc + j*16 + llo;
        float v = acc[i][j][rr];
        if (isb) ((ushort_t*)out)[(size_t)s*NQ + nl] = f2b(v);
        else     ((float*)out)[(size_t)s*NQ + nl] = v;
      }
}

// ---------------------------------------------------------------- Attention v17 (R13/R15 body exactly — best measured)
// 1024 blocks (t,h,kv), single-buffered K/V (33KB LDS), launch_bounds(256,2)
// (~100 VGPR, no spill; 4 blocks/CU co-resident). Single-chain QK, per-rr
// edge mask, exp2 softmax, XCD-kv chunking, coset-balanced t permutation.
__global__ __launch_bounds__(256, 2)
void attn_kernel(const ushort_t* __restrict__ qb, const ushort_t* __restrict__ kb,
                 const ushort_t* __restrict__ vt, float* __restrict__ abf,
                 ushort_t* __restrict__ pb, int use_pb){
  __shared__ __attribute__((aligned(16))) ushort_t lds_k[64*128];
  __shared__ __attribute__((aligned(16))) ushort_t lds_v[128*64];
  __shared__ float lsum[4][32];
  const int tid = threadIdx.x;
  const int wid = tid>>6, lane = tid&63;
  const int l31 = lane&31, hi = lane>>5;
  const int flat = (int)(blockIdx.x + 16*blockIdx.y + 256*blockIdx.z);  // 0..1023
  const int xcd = flat & 7, slot = flat >> 3;                           // slot 0..127
  const int kv = xcd >> 1;                                              // kv per XCD pair
  const int idx = slot*2 + (xcd & 1);                                   // 0..255
  const int g = idx >> 4, h = idx & 15;
  // coset-balanced heavy-first permutation: cosets {g,g+4,g+8,g+12} sum to 30
  const int t = (g<4) ? 15-g : (g<8) ? 4+g : (g<12) ? g-4 : 15-g;
  const ushort_t* kbase = kb + (size_t)kv*SEQ*DH;
  const ushort_t* vbase = vt + (size_t)kv*DH*SEQ;
  const int NKT = 2*t + 2;
  const int qrow0 = t*128 + wid*32;
  const int qg = qrow0 + l31;

  bf16x8 qf[8];
  {
    const ushort_t* qp = qb + (size_t)qg*NQ + h*DH + hi*8;
    #pragma unroll
    for (int ks=0;ks<8;ks++) qf[ks] = *(const bf16x8*)(qp + ks*16);
  }
  f32x16 oacc[4];
  #pragma unroll
  for (int d=0;d<4;d++) oacc[d] = zero16();
  float psum = 0.f;

  for (int kt=0; kt<NKT; ++kt){
    __syncthreads();                    // all waves done reading previous tile
    // stage K [64][128] (swz ^((r&15)<<4)) + V^T [128][64] (swz ^((r&7)<<4))
    #pragma unroll
    for (int pp=0;pp<4;pp++){
      int lin = pp*4096 + tid*16;
      int rk = lin>>8, cbk = lin&255;
      int sck = cbk ^ ((rk&15)<<4);
      gload16(kbase + (size_t)(kt*64 + rk)*DH + (sck>>1), (char*)lds_k + pp*4096 + (wid<<10));
      int rv = lin>>7, cbv = lin&127;
      int scv = cbv ^ ((rv&7)<<4);
      gload16(vbase + (size_t)rv*SEQ + kt*64 + (scv>>1), (char*)lds_v + pp*4096 + (wid<<10));
    }
    __syncthreads();                    // staged (vmcnt(0) drained by barrier)

    #pragma unroll
    for (int ss=0;ss<2;ss++){
      const int kvb = kt*64 + ss*32;
      if (kvb > qrow0 + 31) continue;   // fully masked for this wave
      f32x16 sacc = zero16();
      #pragma unroll
      for (int ks=0;ks<8;ks++){
        int row = ss*32 + l31;
        int boff = row*256 + ((ks*32 + hi*16) ^ ((row&15)<<4));
        bf16x8 kf = *(const bf16x8*)((const char*)lds_k + boff);
        sacc = mfma32(kf, qf[ks], sacc);
      }
      const bool edge = (kvb + 31 > qrow0);
      #pragma unroll
      for (int rr=0; rr<16; rr++){
        float e = EXP2(sacc[rr]);       // exp(qk/sqrt(d)): log2e folded into q scale
        if (edge){
          int kvg = kvb + (rr&3) + 8*(rr>>2) + 4*hi;
          if (kvg > qg) e = 0.f;
        }
        sacc[rr] = e;
        psum += e;
      }
      #pragma unroll
      for (int pk=0; pk<2; pk++){
        uint_t P0, P1, P2, P3;
        asm("v_cvt_pk_bf16_f32 %0, %1, %2" : "=v"(P0) : "v"(sacc[8*pk+0]), "v"(sacc[8*pk+1]));
        asm("v_cvt_pk_bf16_f32 %0, %1, %2" : "=v"(P1) : "v"(sacc[8*pk+2]), "v"(sacc[8*pk+3]));
        asm("v_cvt_pk_bf16_f32 %0, %1, %2" : "=v"(P2) : "v"(sacc[8*pk+4]), "v"(sacc[8*pk+5]));
        asm("v_cvt_pk_bf16_f32 %0, %1, %2" : "=v"(P3) : "v"(sacc[8*pk+6]), "v"(sacc[8*pk+7]));
        asm("v_permlane32_swap_b32 %0, %1" : "+v"(P0), "+v"(P2));
        asm("v_permlane32_swap_b32 %0, %1" : "+v"(P1), "+v"(P3));
        uint4 fu; fu.x = P0; fu.y = P1; fu.z = P2; fu.w = P3;
        bf16x8 pf = *(bf16x8*)&fu;
        #pragma unroll
        for (int d=0; d<4; d++){
          int rowv = d*32 + l31;
          int bv = rowv*128 + ((ss*64 + pk*32 + hi*16) ^ ((rowv&7)<<4));
          bf16x8 vf = *(const bf16x8*)((const char*)lds_v + bv);
          oacc[d] = mfma32(pf, vf, oacc[d]);
        }
      }
    }
  } // kt

  // finalize: row sums, scale by 0.25/l, write partial (or atomic fallback)
  {
    float tot = psum + __shfl_xor(psum, 32);
    lsum[wid][l31] = tot;
    if (use_pb){
      ushort_t* pbk = pb + (size_t)kv*SEQ*NQ + (size_t)h*DH;
      #pragma unroll
      for (int rr=0; rr<16; rr++){
        int qr = (rr&3) + 8*(rr>>2) + 4*hi;
        float sc = 0.25f / lsum[wid][qr];
        #pragma unroll
        for (int d=0; d<4; d++)
          pbk[(size_t)(qrow0 + qr)*NQ + d*32 + l31] = f2b(oacc[d][rr]*sc);
      }
    } else {
      #pragma unroll
      for (int rr=0; rr<16; rr++){
        int qr = (rr&3) + 8*(rr>>2) + 4*hi;
        float sc = 0.25f / lsum[wid][qr];
        #pragma unroll
        for (int d=0; d<4; d++)
          atomicAdd(&abf[(size_t)(qrow0 + qr)*NQ + h*DH + d*32 + l31], oacc[d][rr]*sc);
      }
    }
  }
}

// ---------------------------------------------------------------- launch
extern "C" void kernel_launch(void* const* d_in, const int* in_sizes, int n_in,
                              void* d_out, int out_size, void* d_ws, size_t ws_size,
                              hipStream_t stream) {
  const void* x  = d_in[0];
  const void* wq = d_in[1];
  const void* wk = d_in[2];
  const void* wv = d_in[3];
  const void* wo = d_in[4];
  char* ws = (char*)d_ws;
  const bool big_ws = (ws_size >= ((size_t)55<<20));

  if (big_ws){
    // q 0-8 | k 8-10 | tab 10-11 | vt 12-14 | pb0..3 14-46 | wob 46-54 | flag @54
    // overlays: xb 14-22, wqb 22-30, wkb 30-32, wvb 32-34 (dead after gemm_qkv,
    // before attn writes pb). ab = qbuf (dead after attn).
    ushort_t* qbuf = (ushort_t*)(ws);
    ushort_t* kbuf = (ushort_t*)(ws + ((size_t)8<<20));
    float2*   tab  = (float2*)  (ws + ((size_t)10<<20));
    ushort_t* vtb  = (ushort_t*)(ws + ((size_t)12<<20));
    ushort_t* pbuf = (ushort_t*)(ws + ((size_t)14<<20));
    ushort_t* xb   = (ushort_t*)(ws + ((size_t)14<<20));
    ushort_t* wqb  = (ushort_t*)(ws + ((size_t)22<<20));
    ushort_t* wkb  = (ushort_t*)(ws + ((size_t)30<<20));
    ushort_t* wvb  = (ushort_t*)(ws + ((size_t)32<<20));
    ushort_t* wob  = (ushort_t*)(ws + ((size_t)46<<20));
    ushort_t* ab   = qbuf;
    int* flag      = (int*)(ws + ((size_t)54<<20));

    hipLaunchKernelGGL(prep, dim3(512), dim3(256), 0, stream, (const ushort_t*)wq, flag, tab);
    hipLaunchKernelGGL(cvt_all, dim3(7168), dim3(256), 0, stream, x, wq, wk, wv, wo,
                       xb, wqb, wkb, wvb, wob, flag);
    hipLaunchKernelGGL(gemm_qkv, dim3(768), dim3(256), 0, stream, xb, wqb, wkb, wvb,
                       qbuf, kbuf, vtb, tab);
    hipLaunchKernelGGL(attn_kernel, dim3(16,16,4), dim3(256), 0, stream, qbuf, kbuf, vtb,
                       (float*)nullptr, pbuf, 1);
    hipLaunchKernelGGL(sum4, dim3(2048), dim3(256), 0, stream, pbuf, ab);
    hipLaunchKernelGGL(gemm_plain_b16, dim3(512), dim3(256), 0, stream, ab, wob, d_out, flag);
  } else {
    // atomic fallback: q 0-8 | k 8-10 | tab 10-11 | vt 12-14 | abf 14-30 fp32 |
    // xb 14-22, wqb 22-30 (overlay, dead before memset) | wkb 30-32 | wvb 32-34 |
    // wob 34-42 | flag @42
    ushort_t* qbuf = (ushort_t*)(ws);
    ushort_t* kbuf = (ushort_t*)(ws + ((size_t)8<<20));
    float2*   tab  = (float2*)  (ws + ((size_t)10<<20));
    ushort_t* vtb  = (ushort_t*)(ws + ((size_t)12<<20));
    float*    abf  = (float*)(ws + ((size_t)14<<20));
    ushort_t* xb   = (ushort_t*)(ws + ((size_t)14<<20));
    ushort_t* wqb  = (ushort_t*)(ws + ((size_t)22<<20));
    ushort_t* wkb  = (ushort_t*)(ws + ((size_t)30<<20));
    ushort_t* wvb  = (ushort_t*)(ws + ((size_t)32<<20));
    ushort_t* wob  = (ushort_t*)(ws + ((size_t)34<<20));
    int* flag      = (int*)(ws + ((size_t)42<<20));

    hipLaunchKernelGGL(prep, dim3(512), dim3(256), 0, stream, (const ushort_t*)wq, flag, tab);
    hipLaunchKernelGGL(cvt_all, dim3(7168), dim3(256), 0, stream, x, wq, wk, wv, wo,
                       xb, wqb, wkb, wvb, wob, flag);
    hipLaunchKernelGGL(gemm_qkv, dim3(768), dim3(256), 0, stream, xb, wqb, wkb, wvb,
                       qbuf, kbuf, vtb, tab);
    hipMemsetAsync(abf, 0, (size_t)SEQ*NQ*sizeof(float), stream);
    hipLaunchKernelGGL(attn_kernel, dim3(16,16,4), dim3(256), 0, stream, qbuf, kbuf, vtb,
                       abf, (ushort_t*)nullptr, 0);
    hipLaunchKernelGGL(gemm_plain_f32, dim3(16,16), dim3(256), 0, stream, abf, wob, d_out, flag);
  }
}